// Round 6
// baseline (177.958 us; speedup 1.0000x reference)
//
#include <hip/hip_runtime.h>
#include <hip/hip_bf16.h>

#define BB 2
#define SS 2048
#define DD 768
#define HH 12
#define DHH 64
#define WIN 128
#define MM (BB*SS)

typedef __attribute__((ext_vector_type(8))) short bfrag;
typedef __attribute__((ext_vector_type(4))) float f32x4;
typedef __attribute__((ext_vector_type(4))) short s16x4;

#define AS3(p) ((__attribute__((address_space(3))) void*)(p))
#define AS1(p) ((const __attribute__((address_space(1))) void*)(p))

__device__ inline unsigned short f2bf(float f) {
    union { __hip_bfloat16 h; unsigned short u; } cv;
    cv.h = __float2bfloat16(f);
    return cv.u;
}

// Stage a R x 32 bf16 tile (row-major, global stride DD) into LDS via DMA,
// 16B chunks XOR-swizzled: chunk cs at row goes to slot cs ^ ((row>>1)&3).
__device__ inline void stage128(unsigned short* dst, const unsigned short* src,
                                int w4, int l) {
    #pragma unroll
    for (int j = 0; j < 2; j++) {
        int eoff = (w4 * 2 + j) * 512;
        int e = eoff + l * 8;
        int row = e >> 5;
        int k8 = ((e >> 3) & 3) ^ ((row >> 1) & 3);
        __builtin_amdgcn_global_load_lds(AS1(src + (size_t)row * DD + k8 * 8),
                                         AS3(dst + eoff), 16, 0, 0);
    }
}
__device__ inline void stage64(unsigned short* dst, const unsigned short* src,
                               int w4, int l) {
    int eoff = w4 * 512;
    int e = eoff + l * 8;
    int row = e >> 5;
    int k8 = ((e >> 3) & 3) ^ ((row >> 1) & 3);
    __builtin_amdgcn_global_load_lds(AS1(src + (size_t)row * DD + k8 * 8),
                                     AS3(dst + eoff), 16, 0, 0);
}

// ---------------- Kernel 0: pack (weights + rope only; X handled in qkv) -------
__global__ __launch_bounds__(256) void pack_kernel(
    const float* __restrict__ Wq, const float* __restrict__ Wk, const float* __restrict__ Wv,
    const float* __restrict__ Wo,
    unsigned short* __restrict__ Wt, unsigned short* __restrict__ Wot,
    float2* __restrict__ rope)
{
    __shared__ float T[64][65];
    const int bid = blockIdx.x, t = threadIdx.x;
    if (bid < 432) {
        int proj = bid / 144, rem = bid % 144;
        int h = rem / 12, d0 = (rem % 12) * 64;
        const float* src = (proj == 0 ? Wq : (proj == 1 ? Wk : Wv)) + (size_t)h * DD * DHH;
        int row = t >> 2, c0 = (t & 3) * 16;
        const float4* p4 = reinterpret_cast<const float4*>(src + (size_t)(d0 + row) * DHH + c0);
        float4 x0 = p4[0], x1 = p4[1], x2 = p4[2], x3 = p4[3];
        float* tr = &T[row][c0];
        tr[0]=x0.x; tr[1]=x0.y; tr[2]=x0.z; tr[3]=x0.w;
        tr[4]=x1.x; tr[5]=x1.y; tr[6]=x1.z; tr[7]=x1.w;
        tr[8]=x2.x; tr[9]=x2.y; tr[10]=x2.z; tr[11]=x2.w;
        tr[12]=x3.x; tr[13]=x3.y; tr[14]=x3.z; tr[15]=x3.w;
        __syncthreads();
        int dh = t >> 2;
        unsigned short tmp[16];
        #pragma unroll
        for (int j = 0; j < 16; j++) tmp[j] = f2bf(T[c0 + j][dh]);
        unsigned short* dst = Wt + (size_t)proj * DD * DD + (size_t)(h * 64 + dh) * DD + d0 + c0;
        *reinterpret_cast<bfrag*>(dst)     = *reinterpret_cast<bfrag*>(tmp);
        *reinterpret_cast<bfrag*>(dst + 8) = *reinterpret_cast<bfrag*>(tmp + 8);
    } else if (bid < 576) {
        int id2 = bid - 432;
        int k0 = (id2 / 12) * 64, n0 = (id2 % 12) * 64;
        int row = t >> 2, c0 = (t & 3) * 16;
        const float4* p4 = reinterpret_cast<const float4*>(Wo + (size_t)(k0 + row) * DD + n0 + c0);
        float4 x0 = p4[0], x1 = p4[1], x2 = p4[2], x3 = p4[3];
        float* tr = &T[row][c0];
        tr[0]=x0.x; tr[1]=x0.y; tr[2]=x0.z; tr[3]=x0.w;
        tr[4]=x1.x; tr[5]=x1.y; tr[6]=x1.z; tr[7]=x1.w;
        tr[8]=x2.x; tr[9]=x2.y; tr[10]=x2.z; tr[11]=x2.w;
        tr[12]=x3.x; tr[13]=x3.y; tr[14]=x3.z; tr[15]=x3.w;
        __syncthreads();
        int nr = t >> 2;
        unsigned short tmp[16];
        #pragma unroll
        for (int j = 0; j < 16; j++) tmp[j] = f2bf(T[c0 + j][nr]);
        unsigned short* dst = Wot + (size_t)(n0 + nr) * DD + k0 + c0;
        *reinterpret_cast<bfrag*>(dst)     = *reinterpret_cast<bfrag*>(tmp);
        *reinterpret_cast<bfrag*>(dst + 8) = *reinterpret_cast<bfrag*>(tmp + 8);
    } else {
        int idx = (bid - 576) * 256 + t;   // p in [0,2048), i2 in [0,32)
        int p = idx >> 5, i2 = idx & 31;
        float inv_freq = exp2f(-(float)i2 * (13.287712379549449f / 32.0f));
        float s, c;
        sincosf((float)p * inv_freq, &s, &c);
        rope[idx] = make_float2(s, c);
    }
}

// ---------------- Kernel 1: QKV GEMM 128x128 dbuf; A = in-register fp32->bf16 --
// B via global_load_lds DMA; A: 16 fp32 loads (issued BEFORE the DMA so the
// convert's vmcnt wait doesn't drain the DMA queue) + 2 swizzled ds_write_b128.
__global__ __launch_bounds__(256) void qkv_gemm_kernel(
    const float* __restrict__ Xq, const float* __restrict__ Xk, const float* __restrict__ Xv,
    const unsigned short* __restrict__ Wt,
    const float* __restrict__ bq, const float* __restrict__ bk, const float* __restrict__ bv,
    const float2* __restrict__ rope,
    unsigned short* __restrict__ qo, unsigned short* __restrict__ ko, unsigned short* __restrict__ vo)
{
    const int mt0  = blockIdx.x * 128;
    const int n0   = blockIdx.y * 128;
    const int proj = blockIdx.z;
    const float* X = (proj == 0 ? Xq : (proj == 1 ? Xk : Xv)) + (size_t)mt0 * DD;
    const unsigned short* W = Wt + (size_t)proj * DD * DD + (size_t)n0 * DD;
    const float* bias = proj == 0 ? bq : (proj == 1 ? bk : bv);

    // A0 [0,4096) B0 [4096,8192) A1 [8192,12288) B1 [12288,16384); Ct aliases all
    __shared__ unsigned short smem[128 * 140];

    const int t = threadIdx.x;
    const int l = t & 63, w4 = t >> 6;
    const int l16 = l & 15, quad = l >> 4;
    const int wr = w4 >> 1, wc = w4 & 1;
    const int swz = (l16 >> 1) & 3;

    const int arow = t >> 1, ac0 = (t & 1) * 16;
    const int as_ = (arow >> 1) & 3;
    const int ak8 = ac0 >> 3;   // 0 or 2
    const float* Xrow = X + (size_t)arow * DD + ac0;
    unsigned short* Adst0 = &smem[arow * 32 + ((ak8 ^ as_) * 8)];
    unsigned short* Adst1 = &smem[arow * 32 + (((ak8 + 1) ^ as_) * 8)];

    #define STAGE_A(bufofs, k0)                                                  \
        {                                                                        \
            const float4* p4 = reinterpret_cast<const float4*>(Xrow + (k0));     \
            float4 a0 = p4[0], a1 = p4[1], a2 = p4[2], a3 = p4[3];               \
            unsigned short u[16];                                                \
            u[0]=f2bf(a0.x); u[1]=f2bf(a0.y); u[2]=f2bf(a0.z); u[3]=f2bf(a0.w);  \
            u[4]=f2bf(a1.x); u[5]=f2bf(a1.y); u[6]=f2bf(a1.z); u[7]=f2bf(a1.w);  \
            u[8]=f2bf(a2.x); u[9]=f2bf(a2.y); u[10]=f2bf(a2.z); u[11]=f2bf(a2.w);\
            u[12]=f2bf(a3.x); u[13]=f2bf(a3.y); u[14]=f2bf(a3.z); u[15]=f2bf(a3.w);\
            *reinterpret_cast<bfrag*>(Adst0 + (bufofs)) = *reinterpret_cast<bfrag*>(u);     \
            *reinterpret_cast<bfrag*>(Adst1 + (bufofs)) = *reinterpret_cast<bfrag*>(u + 8); \
        }

    f32x4 acc[16] = {};

    STAGE_A(0, 0)
    stage128(smem + 4096, W, w4, l);

    for (int it = 0; it < 24; ++it) {
        unsigned short* cur = smem + (it & 1) * 8192;
        __syncthreads();   // tile `it` resident; all waves done reading other buf
        if (it < 23) {
            int nb = ((it + 1) & 1) * 8192;
            STAGE_A(nb, (it + 1) * 32)                         // fp32 loads first
            stage128(smem + nb + 4096, W + (it + 1) * 32, w4, l);  // then DMA
        }
        bfrag af[4], bg[4];
        #pragma unroll
        for (int mi = 0; mi < 4; mi++)
            af[mi] = *reinterpret_cast<const bfrag*>(&cur[(wr * 64 + mi * 16 + l16) * 32 + ((quad ^ swz) * 8)]);
        #pragma unroll
        for (int ni = 0; ni < 4; ni++)
            bg[ni] = *reinterpret_cast<const bfrag*>(&cur[4096 + (wc * 64 + ni * 16 + l16) * 32 + ((quad ^ swz) * 8)]);
        #pragma unroll
        for (int mi = 0; mi < 4; mi++)
            #pragma unroll
            for (int ni = 0; ni < 4; ni++)
                acc[mi * 4 + ni] = __builtin_amdgcn_mfma_f32_16x16x32_bf16(af[mi], bg[ni], acc[mi * 4 + ni], 0, 0, 0);
    }
    __syncthreads();
    #undef STAGE_A

    unsigned short* Ct = smem;   // stride 140
    const int b = mt0 >> 11;
    if (proj < 2) {
        #pragma unroll
        for (int ni = 0; ni < 4; ni++) {
            int nloc = wc * 64 + ni * 16 + l16;
            int n = n0 + nloc;
            int dh = n & 63;
            float bv0 = bias[n];
            float bv1 = bias[n ^ 32];
            float sgn = (dh & 32) ? 1.0f : -1.0f;
            const float2* rp = rope + (dh & 31);
            #pragma unroll
            for (int mi = 0; mi < 4; mi++)
                #pragma unroll
                for (int r = 0; r < 4; r++) {
                    int ploc = wr * 64 + mi * 16 + quad * 4 + r;
                    int p = (mt0 + ploc) & (SS - 1);
                    float2 sc = rp[p << 5];
                    float val = acc[mi * 4 + ni][r] + bv0;
                    float pr  = acc[mi * 4 + (ni ^ 2)][r] + bv1;
                    Ct[ploc * 140 + nloc] = f2bf(val * sc.y + sgn * pr * sc.x);
                }
        }
        __syncthreads();
        unsigned short* dst = (proj == 0) ? qo : ko;
        #pragma unroll
        for (int jj = 0; jj < 8; jj++) {
            int id = jj * 256 + t;
            int row = id >> 4, c = (id & 15) * 8;
            int n = n0 + c, h = n >> 6, dh = n & 63;
            int p = (mt0 + row) & (SS - 1);
            bfrag vv = *reinterpret_cast<const bfrag*>(&Ct[row * 140 + c]);
            *reinterpret_cast<bfrag*>(dst + (((size_t)(b * HH + h) * SS + p) << 6) + dh) = vv;
        }
    } else {
        #pragma unroll
        for (int ni = 0; ni < 4; ni++) {
            int nloc = wc * 64 + ni * 16 + l16;
            float bv0 = bias[n0 + nloc];
            #pragma unroll
            for (int mi = 0; mi < 4; mi++)
                #pragma unroll
                for (int r = 0; r < 4; r++) {
                    int ploc = wr * 64 + mi * 16 + quad * 4 + r;
                    Ct[nloc * 140 + ploc] = f2bf(acc[mi * 4 + ni][r] + bv0);
                }
        }
        __syncthreads();
        int p0 = mt0 & (SS - 1);
        #pragma unroll
        for (int jj = 0; jj < 8; jj++) {
            int id = jj * 256 + t;
            int row = id >> 4, c = (id & 15) * 8;
            int n = n0 + row, h = n >> 6, dh = n & 63;
            bfrag vv = *reinterpret_cast<const bfrag*>(&Ct[row * 140 + c]);
            *reinterpret_cast<bfrag*>(vo + (((size_t)(b * HH + h) * DHH + dh) << 11) + p0 + c) = vv;
        }
    }
}

// ---------------- Kernel 2: sliding-window attention (round-5 verified) --------
__global__ __launch_bounds__(256) void attn_kernel(
    const unsigned short* __restrict__ q,
    const unsigned short* __restrict__ k,
    const unsigned short* __restrict__ v,
    unsigned short* __restrict__ z)
{
    const int qb = blockIdx.x * 64;
    const int h  = blockIdx.y;
    const int b  = blockIdx.z;
    const int kb = qb - WIN;   // may be negative: reads land in prior ws slab (masked)

    // K panels [0,12288); P aliases [0,12800); Vt [12800,25088)
    __shared__ unsigned short sA[25088];

    const int t = threadIdx.x;
    const int w4 = t >> 6, l = t & 63;
    const int l16 = l & 15, quad = l >> 4;
    const int swz = (l16 >> 1) & 3;

    const size_t qkbase = (size_t)(b * HH + h) * SS * DHH;
    const unsigned short* kp = (k + qkbase) + (ptrdiff_t)kb * DHH;
    const unsigned short* vp = (v + (size_t)(b * HH + h) * DHH * SS) + (ptrdiff_t)kb;

    #pragma unroll
    for (int j = 0; j < 6; j++) {
        int g = w4 * 6 + j;
        int panel = g >> 2, sub = g & 3;
        int rg = panel >> 1, kpart = panel & 1;
        int e = sub * 512 + l * 8;
        int row = e >> 5;
        int k8 = ((e >> 3) & 3) ^ ((row >> 1) & 3);
        __builtin_amdgcn_global_load_lds(
            AS1(kp + (size_t)(rg * 64 + row) * DHH + kpart * 32 + k8 * 8),
            AS3(sA + panel * 2048 + sub * 512), 16, 0, 0);
    }
    #pragma unroll
    for (int j = 0; j < 6; j++) {
        int g = w4 * 6 + j;
        int F = g * 64 + l;               // flat 16B-chunk id, 0..1535
        int d = F / 24, s = F % 24;
        int cs = s ^ (d & 7);
        __builtin_amdgcn_global_load_lds(
            AS1(vp + (size_t)d * SS + cs * 8),
            AS3(sA + 12800 + g * 512), 16, 0, 0);
    }
    bfrag qf[2];
    #pragma unroll
    for (int kk = 0; kk < 2; kk++)
        qf[kk] = *reinterpret_cast<const bfrag*>(
            q + qkbase + (size_t)(qb + 16 * w4 + l16) * DHH + kk * 32 + quad * 8);

    __syncthreads();   // K + V resident

    f32x4 sacc[12] = {};
    #pragma unroll
    for (int kk = 0; kk < 2; kk++)
        #pragma unroll
        for (int mt = 0; mt < 12; mt++) {
            int kr = 16 * mt + l16;
            bfrag bf = *reinterpret_cast<const bfrag*>(
                &sA[(((kr >> 6) * 2 + kk) * 2048) + (kr & 63) * 32 + ((quad ^ swz) * 8)]);
            sacc[mt] = __builtin_amdgcn_mfma_f32_16x16x32_bf16(qf[kk], bf, sacc[mt], 0, 0, 0);
        }

    float mx[4] = {-3e38f, -3e38f, -3e38f, -3e38f};
    #pragma unroll
    for (int mt = 0; mt < 12; mt++)
        #pragma unroll
        for (int r = 0; r < 4; r++) {
            int row = 16 * w4 + quad * 4 + r;
            int c = 16 * mt + l16;
            bool valid = (c > row) && (c <= row + WIN) && (kb + c >= 0);
            float s = valid ? sacc[mt][r] * 0.125f : -3e38f;
            sacc[mt][r] = s;
            mx[r] = fmaxf(mx[r], s);
        }
    #pragma unroll
    for (int off = 1; off < 16; off <<= 1)
        #pragma unroll
        for (int r = 0; r < 4; r++) mx[r] = fmaxf(mx[r], __shfl_xor(mx[r], off, 64));
    float sum[4] = {0.f, 0.f, 0.f, 0.f};
    #pragma unroll
    for (int mt = 0; mt < 12; mt++)
        #pragma unroll
        for (int r = 0; r < 4; r++) {
            float p = __expf(sacc[mt][r] - mx[r]);
            sacc[mt][r] = p;
            sum[r] += p;
        }
    #pragma unroll
    for (int off = 1; off < 16; off <<= 1)
        #pragma unroll
        for (int r = 0; r < 4; r++) sum[r] += __shfl_xor(sum[r], off, 64);
    float inv[4];
    #pragma unroll
    for (int r = 0; r < 4; r++) inv[r] = 1.0f / sum[r];

    __syncthreads();   // all K reads done before P overwrites that region

    unsigned short* Ps = sA;
    #pragma unroll
    for (int mt = 0; mt < 12; mt++)
        #pragma unroll
        for (int r = 0; r < 4; r++)
            Ps[(16 * w4 + quad * 4 + r) * 200 + 16 * mt + l16] = f2bf(sacc[mt][r] * inv[r]);

    unsigned short* Vt = sA + 12800;
    f32x4 zacc[4] = {};
    #pragma unroll
    for (int ci = 0; ci < 6; ci++) {
        bfrag pb = *reinterpret_cast<const bfrag*>(
            &Ps[(16 * w4 + l16) * 200 + ci * 32 + quad * 8]);
        #pragma unroll
        for (int mt = 0; mt < 4; mt++) {
            int d = 16 * mt + l16;
            bfrag va = *reinterpret_cast<const bfrag*>(
                &Vt[d * 192 + (((ci * 4 + quad) ^ (l16 & 7)) * 8)]);
            zacc[mt] = __builtin_amdgcn_mfma_f32_16x16x32_bf16(va, pb, zacc[mt], 0, 0, 0);
        }
    }
    size_t zrow = ((size_t)(b * SS + qb + 16 * w4 + l16)) * (HH * DHH) + h * DHH;
    #pragma unroll
    for (int mt = 0; mt < 4; mt++) {
        s16x4 pk;
        pk[0] = (short)f2bf(zacc[mt][0]);
        pk[1] = (short)f2bf(zacc[mt][1]);
        pk[2] = (short)f2bf(zacc[mt][2]);
        pk[3] = (short)f2bf(zacc[mt][3]);
        *reinterpret_cast<s16x4*>(z + zrow + 16 * mt + quad * 4) = pk;
    }
}

// ---------------- Kernel 3: output projection, 64x128 tile, dbuf DMA ----------
__global__ __launch_bounds__(256) void out_gemm_kernel(
    const unsigned short* __restrict__ Z,
    const unsigned short* __restrict__ Wot,
    const float* __restrict__ bo,
    float* __restrict__ out)
{
    const int mt0 = blockIdx.x * 64;
    const int n0  = blockIdx.y * 128;
    const unsigned short* A = Z + (size_t)mt0 * DD;
    const unsigned short* Bw = Wot + (size_t)n0 * DD;

    __shared__ unsigned short smem[12288];

    const int t = threadIdx.x;
    const int l = t & 63, w4 = t >> 6;
    const int l16 = l & 15, quad = l >> 4;
    const int swz = (l16 >> 1) & 3;

    f32x4 acc[8] = {};

    stage64 (smem,        A,  w4, l);
    stage128(smem + 2048, Bw, w4, l);

    for (int it = 0; it < 24; ++it) {
        unsigned short* Ac = smem + (it & 1) * 6144;
        unsigned short* Bc = Ac + 2048;
        __syncthreads();
        if (it < 23) {
            unsigned short* An = smem + ((it + 1) & 1) * 6144;
            stage64 (An,        A  + (it + 1) * 32, w4, l);
            stage128(An + 2048, Bw + (it + 1) * 32, w4, l);
        }
        bfrag af[4], bg[2];
        #pragma unroll
        for (int mi = 0; mi < 4; mi++)
            af[mi] = *reinterpret_cast<const bfrag*>(&Ac[(mi * 16 + l16) * 32 + ((quad ^ swz) * 8)]);
        #pragma unroll
        for (int ni = 0; ni < 2; ni++)
            bg[ni] = *reinterpret_cast<const bfrag*>(&Bc[(w4 * 32 + ni * 16 + l16) * 32 + ((quad ^ swz) * 8)]);
        #pragma unroll
        for (int mi = 0; mi < 4; mi++)
            #pragma unroll
            for (int ni = 0; ni < 2; ni++)
                acc[mi * 2 + ni] = __builtin_amdgcn_mfma_f32_16x16x32_bf16(af[mi], bg[ni], acc[mi * 2 + ni], 0, 0, 0);
    }

    #pragma unroll
    for (int ni = 0; ni < 2; ni++) {
        int n = n0 + w4 * 32 + ni * 16 + l16;
        float bv0 = bo[n];
        #pragma unroll
        for (int mi = 0; mi < 4; mi++)
            #pragma unroll
            for (int r = 0; r < 4; r++) {
                int m = mt0 + mi * 16 + quad * 4 + r;
                out[(size_t)m * DD + n] = acc[mi * 2 + ni][r] + bv0;
            }
    }
}

extern "C" void kernel_launch(void* const* d_in, const int* in_sizes, int n_in,
                              void* d_out, int out_size, void* d_ws, size_t ws_size,
                              hipStream_t stream) {
    const float* Xq = (const float*)d_in[0];
    const float* Xk = (const float*)d_in[1];
    const float* Xv = (const float*)d_in[2];
    const float* Wq = (const float*)d_in[3];
    const float* Wk = (const float*)d_in[4];
    const float* Wv = (const float*)d_in[5];
    const float* Wo = (const float*)d_in[6];
    const float* bq = (const float*)d_in[7];
    const float* bk = (const float*)d_in[8];
    const float* bv = (const float*)d_in[9];
    const float* bo = (const float*)d_in[10];
    float* out = (float*)d_out;

    const size_t seg = (size_t)BB * HH * SS * DHH;   // 3,145,728 bf16 elems
    unsigned short* q   = (unsigned short*)d_ws;
    unsigned short* k   = q + seg;
    unsigned short* v   = k + seg;
    unsigned short* z   = v + seg;
    unsigned short* Wt  = z + seg;                    // 3*768*768
    unsigned short* Wot = Wt + (size_t)3 * DD * DD;   // 768*768
    float2* rope = (float2*)(Wot + (size_t)DD * DD);  // 2048*32 float2

    pack_kernel<<<dim3(832), 256, 0, stream>>>(Wq, Wk, Wv, Wo, Wt, Wot, rope);
    qkv_gemm_kernel<<<dim3(MM / 128, DD / 128, 3), 256, 0, stream>>>(
        Xq, Xk, Xv, Wt, bq, bk, bv, rope, q, k, v);
    attn_kernel<<<dim3(SS / 64, HH, BB), 256, 0, stream>>>(q, k, v, z);
    out_gemm_kernel<<<dim3(MM / 64, DD / 128), 256, 0, stream>>>(z, Wot, bo, out);
}

// Round 7
// 163.292 us; speedup vs baseline: 1.0898x; 1.0898x over previous
//
#include <hip/hip_runtime.h>
#include <hip/hip_bf16.h>

#define BB 2
#define SS 2048
#define DD 768
#define HH 12
#define DHH 64
#define WIN 128
#define MM (BB*SS)

typedef __attribute__((ext_vector_type(8))) short bfrag;
typedef __attribute__((ext_vector_type(4))) float f32x4;
typedef __attribute__((ext_vector_type(4))) short s16x4;

#define AS3(p) ((__attribute__((address_space(3))) void*)(p))
#define AS1(p) ((const __attribute__((address_space(1))) void*)(p))

__device__ inline unsigned short f2bf(float f) {
    union { __hip_bfloat16 h; unsigned short u; } cv;
    cv.h = __float2bfloat16(f);
    return cv.u;
}

// Stage a R x 32 bf16 tile (row-major, global stride DD) into LDS via DMA,
// 16B chunks XOR-swizzled: chunk cs at row goes to slot cs ^ ((row>>1)&3).
__device__ inline void stage128(unsigned short* dst, const unsigned short* src,
                                int w4, int l) {
    #pragma unroll
    for (int j = 0; j < 2; j++) {
        int eoff = (w4 * 2 + j) * 512;
        int e = eoff + l * 8;
        int row = e >> 5;
        int k8 = ((e >> 3) & 3) ^ ((row >> 1) & 3);
        __builtin_amdgcn_global_load_lds(AS1(src + (size_t)row * DD + k8 * 8),
                                         AS3(dst + eoff), 16, 0, 0);
    }
}
__device__ inline void stage64(unsigned short* dst, const unsigned short* src,
                               int w4, int l) {
    int eoff = w4 * 512;
    int e = eoff + l * 8;
    int row = e >> 5;
    int k8 = ((e >> 3) & 3) ^ ((row >> 1) & 3);
    __builtin_amdgcn_global_load_lds(AS1(src + (size_t)row * DD + k8 * 8),
                                     AS3(dst + eoff), 16, 0, 0);
}

// ---------------- Kernel 0: pack (round-5 verified) ----------------
// [0,432): W_{Q,K,V} -> Wt ; [432,576): W_O -> Wot ; [576,832): rope ;
// [832,3136): X fp32 -> bf16
__global__ __launch_bounds__(256) void pack_kernel(
    const float* __restrict__ Xq, const float* __restrict__ Xk, const float* __restrict__ Xv,
    const float* __restrict__ Wq, const float* __restrict__ Wk, const float* __restrict__ Wv,
    const float* __restrict__ Wo,
    unsigned short* __restrict__ Wt, unsigned short* __restrict__ Wot,
    float2* __restrict__ rope, unsigned short* __restrict__ Xbf)
{
    __shared__ float T[64][65];
    const int bid = blockIdx.x, t = threadIdx.x;
    if (bid < 432) {
        int proj = bid / 144, rem = bid % 144;
        int h = rem / 12, d0 = (rem % 12) * 64;
        const float* src = (proj == 0 ? Wq : (proj == 1 ? Wk : Wv)) + (size_t)h * DD * DHH;
        int row = t >> 2, c0 = (t & 3) * 16;
        const float4* p4 = reinterpret_cast<const float4*>(src + (size_t)(d0 + row) * DHH + c0);
        float4 x0 = p4[0], x1 = p4[1], x2 = p4[2], x3 = p4[3];
        float* tr = &T[row][c0];
        tr[0]=x0.x; tr[1]=x0.y; tr[2]=x0.z; tr[3]=x0.w;
        tr[4]=x1.x; tr[5]=x1.y; tr[6]=x1.z; tr[7]=x1.w;
        tr[8]=x2.x; tr[9]=x2.y; tr[10]=x2.z; tr[11]=x2.w;
        tr[12]=x3.x; tr[13]=x3.y; tr[14]=x3.z; tr[15]=x3.w;
        __syncthreads();
        int dh = t >> 2;
        unsigned short tmp[16];
        #pragma unroll
        for (int j = 0; j < 16; j++) tmp[j] = f2bf(T[c0 + j][dh]);
        unsigned short* dst = Wt + (size_t)proj * DD * DD + (size_t)(h * 64 + dh) * DD + d0 + c0;
        *reinterpret_cast<bfrag*>(dst)     = *reinterpret_cast<bfrag*>(tmp);
        *reinterpret_cast<bfrag*>(dst + 8) = *reinterpret_cast<bfrag*>(tmp + 8);
    } else if (bid < 576) {
        int id2 = bid - 432;
        int k0 = (id2 / 12) * 64, n0 = (id2 % 12) * 64;
        int row = t >> 2, c0 = (t & 3) * 16;
        const float4* p4 = reinterpret_cast<const float4*>(Wo + (size_t)(k0 + row) * DD + n0 + c0);
        float4 x0 = p4[0], x1 = p4[1], x2 = p4[2], x3 = p4[3];
        float* tr = &T[row][c0];
        tr[0]=x0.x; tr[1]=x0.y; tr[2]=x0.z; tr[3]=x0.w;
        tr[4]=x1.x; tr[5]=x1.y; tr[6]=x1.z; tr[7]=x1.w;
        tr[8]=x2.x; tr[9]=x2.y; tr[10]=x2.z; tr[11]=x2.w;
        tr[12]=x3.x; tr[13]=x3.y; tr[14]=x3.z; tr[15]=x3.w;
        __syncthreads();
        int nr = t >> 2;
        unsigned short tmp[16];
        #pragma unroll
        for (int j = 0; j < 16; j++) tmp[j] = f2bf(T[c0 + j][nr]);
        unsigned short* dst = Wot + (size_t)(n0 + nr) * DD + k0 + c0;
        *reinterpret_cast<bfrag*>(dst)     = *reinterpret_cast<bfrag*>(tmp);
        *reinterpret_cast<bfrag*>(dst + 8) = *reinterpret_cast<bfrag*>(tmp + 8);
    } else if (bid < 832) {
        int idx = (bid - 576) * 256 + t;   // p in [0,2048), i2 in [0,32)
        int p = idx >> 5, i2 = idx & 31;
        float inv_freq = exp2f(-(float)i2 * (13.287712379549449f / 32.0f));
        float s, c;
        sincosf((float)p * inv_freq, &s, &c);
        rope[idx] = make_float2(s, c);
    } else {
        int i = bid - 832;                  // 2304 blocks x 4096 elems
        int proj = i / 768;
        size_t off = (size_t)(i % 768) * 4096 + t * 16;
        const float* src = (proj == 0 ? Xq : (proj == 1 ? Xk : Xv)) + off;
        const float4* p4 = reinterpret_cast<const float4*>(src);
        float4 a0 = p4[0], a1 = p4[1], a2 = p4[2], a3 = p4[3];
        unsigned short u[16];
        u[0]=f2bf(a0.x); u[1]=f2bf(a0.y); u[2]=f2bf(a0.z); u[3]=f2bf(a0.w);
        u[4]=f2bf(a1.x); u[5]=f2bf(a1.y); u[6]=f2bf(a1.z); u[7]=f2bf(a1.w);
        u[8]=f2bf(a2.x); u[9]=f2bf(a2.y); u[10]=f2bf(a2.z); u[11]=f2bf(a2.w);
        u[12]=f2bf(a3.x); u[13]=f2bf(a3.y); u[14]=f2bf(a3.z); u[15]=f2bf(a3.w);
        unsigned short* dst = Xbf + (size_t)proj * MM * DD + off;
        *reinterpret_cast<bfrag*>(dst)     = *reinterpret_cast<bfrag*>(u);
        *reinterpret_cast<bfrag*>(dst + 8) = *reinterpret_cast<bfrag*>(u + 8);
    }
}

// ---------------- Kernel 1: QKV GEMM 128x128 (dbuf DMA) + bias + RoPE ----------
// (round-5 verified: pure-DMA staging; do NOT mix ds_writes into the stage phase)
__global__ __launch_bounds__(256) void qkv_gemm_kernel(
    const unsigned short* __restrict__ Xbf,
    const unsigned short* __restrict__ Wt,
    const float* __restrict__ bq, const float* __restrict__ bk, const float* __restrict__ bv,
    const float2* __restrict__ rope,
    unsigned short* __restrict__ qo, unsigned short* __restrict__ ko, unsigned short* __restrict__ vo)
{
    const int mt0  = blockIdx.x * 128;
    const int n0   = blockIdx.y * 128;
    const int proj = blockIdx.z;
    const unsigned short* X = Xbf + (size_t)proj * MM * DD + (size_t)mt0 * DD;
    const unsigned short* W = Wt + (size_t)proj * DD * DD + (size_t)n0 * DD;
    const float* bias = proj == 0 ? bq : (proj == 1 ? bk : bv);

    __shared__ unsigned short smem[128 * 140];

    const int t = threadIdx.x;
    const int l = t & 63, w4 = t >> 6;
    const int l16 = l & 15, quad = l >> 4;
    const int wr = w4 >> 1, wc = w4 & 1;
    const int swz = (l16 >> 1) & 3;

    f32x4 acc[16] = {};

    stage128(smem,        X, w4, l);
    stage128(smem + 4096, W, w4, l);

    for (int it = 0; it < 24; ++it) {
        unsigned short* Ac = smem + (it & 1) * 8192;
        unsigned short* Bc = Ac + 4096;
        __syncthreads();
        if (it < 23) {
            unsigned short* An = smem + ((it + 1) & 1) * 8192;
            stage128(An,        X + (it + 1) * 32, w4, l);
            stage128(An + 4096, W + (it + 1) * 32, w4, l);
        }
        bfrag af[4], bg[4];
        #pragma unroll
        for (int mi = 0; mi < 4; mi++)
            af[mi] = *reinterpret_cast<const bfrag*>(&Ac[(wr * 64 + mi * 16 + l16) * 32 + ((quad ^ swz) * 8)]);
        #pragma unroll
        for (int ni = 0; ni < 4; ni++)
            bg[ni] = *reinterpret_cast<const bfrag*>(&Bc[(wc * 64 + ni * 16 + l16) * 32 + ((quad ^ swz) * 8)]);
        #pragma unroll
        for (int mi = 0; mi < 4; mi++)
            #pragma unroll
            for (int ni = 0; ni < 4; ni++)
                acc[mi * 4 + ni] = __builtin_amdgcn_mfma_f32_16x16x32_bf16(af[mi], bg[ni], acc[mi * 4 + ni], 0, 0, 0);
    }
    __syncthreads();

    unsigned short* Ct = smem;   // stride 140
    const int b = mt0 >> 11;
    if (proj < 2) {
        #pragma unroll
        for (int ni = 0; ni < 4; ni++) {
            int nloc = wc * 64 + ni * 16 + l16;
            int n = n0 + nloc;
            int dh = n & 63;
            float bv0 = bias[n];
            float bv1 = bias[n ^ 32];
            float sgn = (dh & 32) ? 1.0f : -1.0f;
            const float2* rp = rope + (dh & 31);
            #pragma unroll
            for (int mi = 0; mi < 4; mi++)
                #pragma unroll
                for (int r = 0; r < 4; r++) {
                    int ploc = wr * 64 + mi * 16 + quad * 4 + r;
                    int p = (mt0 + ploc) & (SS - 1);
                    float2 sc = rp[p << 5];
                    float val = acc[mi * 4 + ni][r] + bv0;
                    float pr  = acc[mi * 4 + (ni ^ 2)][r] + bv1;
                    Ct[ploc * 140 + nloc] = f2bf(val * sc.y + sgn * pr * sc.x);
                }
        }
        __syncthreads();
        unsigned short* dst = (proj == 0) ? qo : ko;
        #pragma unroll
        for (int jj = 0; jj < 8; jj++) {
            int id = jj * 256 + t;
            int row = id >> 4, c = (id & 15) * 8;
            int n = n0 + c, h = n >> 6, dh = n & 63;
            int p = (mt0 + row) & (SS - 1);
            bfrag vv = *reinterpret_cast<const bfrag*>(&Ct[row * 140 + c]);
            *reinterpret_cast<bfrag*>(dst + (((size_t)(b * HH + h) * SS + p) << 6) + dh) = vv;
        }
    } else {
        #pragma unroll
        for (int ni = 0; ni < 4; ni++) {
            int nloc = wc * 64 + ni * 16 + l16;
            float bv0 = bias[n0 + nloc];
            #pragma unroll
            for (int mi = 0; mi < 4; mi++)
                #pragma unroll
                for (int r = 0; r < 4; r++) {
                    int ploc = wr * 64 + mi * 16 + quad * 4 + r;
                    Ct[nloc * 140 + ploc] = f2bf(acc[mi * 4 + ni][r] + bv0);
                }
        }
        __syncthreads();
        int p0 = mt0 & (SS - 1);
        #pragma unroll
        for (int jj = 0; jj < 8; jj++) {
            int id = jj * 256 + t;
            int row = id >> 4, c = (id & 15) * 8;
            int n = n0 + row, h = n >> 6, dh = n & 63;
            bfrag vv = *reinterpret_cast<const bfrag*>(&Ct[row * 140 + c]);
            *reinterpret_cast<bfrag*>(vo + (((size_t)(b * HH + h) * DHH + dh) << 11) + p0 + c) = vv;
        }
    }
}

// ---------------- Kernel 2: sliding-window attention (round-5 verified) --------
__global__ __launch_bounds__(256) void attn_kernel(
    const unsigned short* __restrict__ q,
    const unsigned short* __restrict__ k,
    const unsigned short* __restrict__ v,
    unsigned short* __restrict__ z)
{
    const int qb = blockIdx.x * 64;
    const int h  = blockIdx.y;
    const int b  = blockIdx.z;
    const int kb = qb - WIN;   // may be negative: reads land in prior ws slab (masked)

    // K panels [0,12288); P aliases [0,12800); Vt [12800,25088)
    __shared__ unsigned short sA[25088];

    const int t = threadIdx.x;
    const int w4 = t >> 6, l = t & 63;
    const int l16 = l & 15, quad = l >> 4;
    const int swz = (l16 >> 1) & 3;

    const size_t qkbase = (size_t)(b * HH + h) * SS * DHH;
    const unsigned short* kp = (k + qkbase) + (ptrdiff_t)kb * DHH;
    const unsigned short* vp = (v + (size_t)(b * HH + h) * DHH * SS) + (ptrdiff_t)kb;

    #pragma unroll
    for (int j = 0; j < 6; j++) {
        int g = w4 * 6 + j;
        int panel = g >> 2, sub = g & 3;
        int rg = panel >> 1, kpart = panel & 1;
        int e = sub * 512 + l * 8;
        int row = e >> 5;
        int k8 = ((e >> 3) & 3) ^ ((row >> 1) & 3);
        __builtin_amdgcn_global_load_lds(
            AS1(kp + (size_t)(rg * 64 + row) * DHH + kpart * 32 + k8 * 8),
            AS3(sA + panel * 2048 + sub * 512), 16, 0, 0);
    }
    #pragma unroll
    for (int j = 0; j < 6; j++) {
        int g = w4 * 6 + j;
        int F = g * 64 + l;               // flat 16B-chunk id, 0..1535
        int d = F / 24, s = F % 24;
        int cs = s ^ (d & 7);
        __builtin_amdgcn_global_load_lds(
            AS1(vp + (size_t)d * SS + cs * 8),
            AS3(sA + 12800 + g * 512), 16, 0, 0);
    }
    bfrag qf[2];
    #pragma unroll
    for (int kk = 0; kk < 2; kk++)
        qf[kk] = *reinterpret_cast<const bfrag*>(
            q + qkbase + (size_t)(qb + 16 * w4 + l16) * DHH + kk * 32 + quad * 8);

    __syncthreads();   // K + V resident

    f32x4 sacc[12] = {};
    #pragma unroll
    for (int kk = 0; kk < 2; kk++)
        #pragma unroll
        for (int mt = 0; mt < 12; mt++) {
            int kr = 16 * mt + l16;
            bfrag bf = *reinterpret_cast<const bfrag*>(
                &sA[(((kr >> 6) * 2 + kk) * 2048) + (kr & 63) * 32 + ((quad ^ swz) * 8)]);
            sacc[mt] = __builtin_amdgcn_mfma_f32_16x16x32_bf16(qf[kk], bf, sacc[mt], 0, 0, 0);
        }

    float mx[4] = {-3e38f, -3e38f, -3e38f, -3e38f};
    #pragma unroll
    for (int mt = 0; mt < 12; mt++)
        #pragma unroll
        for (int r = 0; r < 4; r++) {
            int row = 16 * w4 + quad * 4 + r;
            int c = 16 * mt + l16;
            bool valid = (c > row) && (c <= row + WIN) && (kb + c >= 0);
            float s = valid ? sacc[mt][r] * 0.125f : -3e38f;
            sacc[mt][r] = s;
            mx[r] = fmaxf(mx[r], s);
        }
    #pragma unroll
    for (int off = 1; off < 16; off <<= 1)
        #pragma unroll
        for (int r = 0; r < 4; r++) mx[r] = fmaxf(mx[r], __shfl_xor(mx[r], off, 64));
    float sum[4] = {0.f, 0.f, 0.f, 0.f};
    #pragma unroll
    for (int mt = 0; mt < 12; mt++)
        #pragma unroll
        for (int r = 0; r < 4; r++) {
            float p = __expf(sacc[mt][r] - mx[r]);
            sacc[mt][r] = p;
            sum[r] += p;
        }
    #pragma unroll
    for (int off = 1; off < 16; off <<= 1)
        #pragma unroll
        for (int r = 0; r < 4; r++) sum[r] += __shfl_xor(sum[r], off, 64);
    float inv[4];
    #pragma unroll
    for (int r = 0; r < 4; r++) inv[r] = 1.0f / sum[r];

    __syncthreads();   // all K reads done before P overwrites that region

    unsigned short* Ps = sA;
    #pragma unroll
    for (int mt = 0; mt < 12; mt++)
        #pragma unroll
        for (int r = 0; r < 4; r++)
            Ps[(16 * w4 + quad * 4 + r) * 200 + 16 * mt + l16] = f2bf(sacc[mt][r] * inv[r]);

    unsigned short* Vt = sA + 12800;
    f32x4 zacc[4] = {};
    #pragma unroll
    for (int ci = 0; ci < 6; ci++) {
        bfrag pb = *reinterpret_cast<const bfrag*>(
            &Ps[(16 * w4 + l16) * 200 + ci * 32 + quad * 8]);
        #pragma unroll
        for (int mt = 0; mt < 4; mt++) {
            int d = 16 * mt + l16;
            bfrag va = *reinterpret_cast<const bfrag*>(
                &Vt[d * 192 + (((ci * 4 + quad) ^ (l16 & 7)) * 8)]);
            zacc[mt] = __builtin_amdgcn_mfma_f32_16x16x32_bf16(va, pb, zacc[mt], 0, 0, 0);
        }
    }
    size_t zrow = ((size_t)(b * SS + qb + 16 * w4 + l16)) * (HH * DHH) + h * DHH;
    #pragma unroll
    for (int mt = 0; mt < 4; mt++) {
        s16x4 pk;
        pk[0] = (short)f2bf(zacc[mt][0]);
        pk[1] = (short)f2bf(zacc[mt][1]);
        pk[2] = (short)f2bf(zacc[mt][2]);
        pk[3] = (short)f2bf(zacc[mt][3]);
        *reinterpret_cast<s16x4*>(z + zrow + 16 * mt + quad * 4) = pk;
    }
}

// ---------------- Kernel 3: output projection, 64x64 tile, even 3 blocks/CU ----
// 768 blocks = exactly 3.0/CU (was 384 = 1.5/CU, uneven). LDS 16KB dbuf,
// ~40 VGPR, 12 waves/CU. Wave w handles m-strip w*16; 4 MFMA/iter.
__global__ __launch_bounds__(256) void out_gemm_kernel(
    const unsigned short* __restrict__ Z,
    const unsigned short* __restrict__ Wot,
    const float* __restrict__ bo,
    float* __restrict__ out)
{
    const int mt0 = blockIdx.x * 64;
    const int n0  = blockIdx.y * 64;
    const unsigned short* A = Z + (size_t)mt0 * DD;
    const unsigned short* Bw = Wot + (size_t)n0 * DD;

    // buf0: A[0,2048) B[2048,4096); buf1: [4096,8192)
    __shared__ unsigned short smem[8192];

    const int t = threadIdx.x;
    const int l = t & 63, w4 = t >> 6;
    const int l16 = l & 15, quad = l >> 4;
    const int swz = (l16 >> 1) & 3;

    f32x4 acc[4] = {};

    stage64(smem,        A,  w4, l);
    stage64(smem + 2048, Bw, w4, l);

    for (int it = 0; it < 24; ++it) {
        unsigned short* Ac = smem + (it & 1) * 4096;
        unsigned short* Bc = Ac + 2048;
        __syncthreads();
        if (it < 23) {
            unsigned short* An = smem + ((it + 1) & 1) * 4096;
            stage64(An,        A  + (it + 1) * 32, w4, l);
            stage64(An + 2048, Bw + (it + 1) * 32, w4, l);
        }
        bfrag af = *reinterpret_cast<const bfrag*>(&Ac[(w4 * 16 + l16) * 32 + ((quad ^ swz) * 8)]);
        #pragma unroll
        for (int ni = 0; ni < 4; ni++) {
            bfrag bg = *reinterpret_cast<const bfrag*>(&Bc[(ni * 16 + l16) * 32 + ((quad ^ swz) * 8)]);
            acc[ni] = __builtin_amdgcn_mfma_f32_16x16x32_bf16(af, bg, acc[ni], 0, 0, 0);
        }
    }

    #pragma unroll
    for (int ni = 0; ni < 4; ni++) {
        int n = n0 + ni * 16 + l16;
        float bv0 = bo[n];
        #pragma unroll
        for (int r = 0; r < 4; r++) {
            int m = mt0 + w4 * 16 + quad * 4 + r;
            out[(size_t)m * DD + n] = acc[ni][r] + bv0;
        }
    }
}

extern "C" void kernel_launch(void* const* d_in, const int* in_sizes, int n_in,
                              void* d_out, int out_size, void* d_ws, size_t ws_size,
                              hipStream_t stream) {
    const float* Xq = (const float*)d_in[0];
    const float* Xk = (const float*)d_in[1];
    const float* Xv = (const float*)d_in[2];
    const float* Wq = (const float*)d_in[3];
    const float* Wk = (const float*)d_in[4];
    const float* Wv = (const float*)d_in[5];
    const float* Wo = (const float*)d_in[6];
    const float* bq = (const float*)d_in[7];
    const float* bk = (const float*)d_in[8];
    const float* bv = (const float*)d_in[9];
    const float* bo = (const float*)d_in[10];
    float* out = (float*)d_out;

    const size_t seg = (size_t)BB * HH * SS * DHH;   // 3,145,728 bf16 elems
    unsigned short* q   = (unsigned short*)d_ws;
    unsigned short* k   = q + seg;
    unsigned short* v   = k + seg;
    unsigned short* z   = v + seg;
    unsigned short* Wt  = z + seg;                    // 3*768*768
    unsigned short* Wot = Wt + (size_t)3 * DD * DD;   // 768*768
    float2* rope = (float2*)(Wot + (size_t)DD * DD);  // 2048*32 float2
    unsigned short* Xbf = (unsigned short*)(rope + 2048 * 32); // 3*4096*768

    pack_kernel<<<dim3(3136), 256, 0, stream>>>(Xq, Xk, Xv, Wq, Wk, Wv, Wo, Wt, Wot, rope, Xbf);
    qkv_gemm_kernel<<<dim3(MM / 128, DD / 128, 3), 256, 0, stream>>>(
        Xbf, Wt, bq, bk, bv, rope, q, k, v);
    attn_kernel<<<dim3(SS / 64, HH, BB), 256, 0, stream>>>(q, k, v, z);
    out_gemm_kernel<<<dim3(MM / 64, DD / 64), 256, 0, stream>>>(z, Wot, bo, out);
}